// Round 1
// baseline (5707.130 us; speedup 1.0000x reference)
//
#include <hip/hip_runtime.h>
#include <math.h>

#define NN 500000
#define NE 16000000
#define SCAN_BLOCK 256
#define NB_SCAN ((NN + SCAN_BLOCK - 1) / SCAN_BLOCK)   // 1954

// ---------------- preprocessing ----------------

__global__ void count_deg(const int4* __restrict__ dst4, int* __restrict__ cnt) {
    int t = blockIdx.x * blockDim.x + threadIdx.x;     // exactly NE/4 threads
    int4 d = dst4[t];
    atomicAdd(&cnt[d.x], 1);
    atomicAdd(&cnt[d.y], 1);
    atomicAdd(&cnt[d.z], 1);
    atomicAdd(&cnt[d.w], 1);
}

__global__ void scan1(const int* __restrict__ cnt, int* __restrict__ rp,
                      int* __restrict__ bsum) {
    __shared__ int sh[SCAN_BLOCK];
    int i = blockIdx.x * SCAN_BLOCK + threadIdx.x;
    int v = (i < NN) ? cnt[i] : 0;
    sh[threadIdx.x] = v;
    __syncthreads();
    for (int off = 1; off < SCAN_BLOCK; off <<= 1) {
        int t = (threadIdx.x >= off) ? sh[threadIdx.x - off] : 0;
        __syncthreads();
        sh[threadIdx.x] += t;
        __syncthreads();
    }
    int incl = sh[threadIdx.x];
    if (i < NN) rp[i] = incl - v;                       // block-local exclusive
    if (threadIdx.x == SCAN_BLOCK - 1) bsum[blockIdx.x] = incl;
}

__global__ void scan2(int* __restrict__ bsum) {
    __shared__ int sh[SCAN_BLOCK];
    __shared__ int carry_sh;
    if (threadIdx.x == 0) carry_sh = 0;
    __syncthreads();
    for (int base = 0; base < NB_SCAN; base += SCAN_BLOCK) {
        int i = base + threadIdx.x;
        int v = (i < NB_SCAN) ? bsum[i] : 0;
        sh[threadIdx.x] = v;
        __syncthreads();
        for (int off = 1; off < SCAN_BLOCK; off <<= 1) {
            int t = (threadIdx.x >= off) ? sh[threadIdx.x - off] : 0;
            __syncthreads();
            sh[threadIdx.x] += t;
            __syncthreads();
        }
        int incl = sh[threadIdx.x];
        int c = carry_sh;
        __syncthreads();
        if (i < NB_SCAN) bsum[i] = c + incl - v;        // global exclusive
        if (threadIdx.x == SCAN_BLOCK - 1) carry_sh = c + incl;
        __syncthreads();
    }
}

__global__ void finalize_scan(const int* __restrict__ cnt, int* __restrict__ rp,
                              const int* __restrict__ bsum, int* __restrict__ cursor,
                              float* __restrict__ dis) {
    int i = blockIdx.x * SCAN_BLOCK + threadIdx.x;
    if (i < NN) {
        int r = rp[i] + bsum[i / SCAN_BLOCK];
        rp[i] = r;
        cursor[i] = r;
        dis[i] = rsqrtf((float)(cnt[i] + 1));           // +1 self loop
    }
    if (blockIdx.x == 0 && threadIdx.x == 0) rp[NN] = NE;
}

__global__ void scatter_edges(const int4* __restrict__ src4, const int4* __restrict__ dst4,
                              int* __restrict__ cursor, int* __restrict__ csr) {
    int t = blockIdx.x * blockDim.x + threadIdx.x;      // exactly NE/4 threads
    int4 s = src4[t];
    int4 d = dst4[t];
    csr[atomicAdd(&cursor[d.x], 1)] = s.x;
    csr[atomicAdd(&cursor[d.y], 1)] = s.y;
    csr[atomicAdd(&cursor[d.z], 1)] = s.z;
    csr[atomicAdd(&cursor[d.w], 1)] = s.w;
}

__global__ void init_z(const float* __restrict__ x0, const float* __restrict__ dis,
                       float* __restrict__ z) {
    int i = blockIdx.x * SCAN_BLOCK + threadIdx.x;
    if (i < NN) z[i] = x0[i] * dis[i];
}

// ---------------- per-layer SpMV (CSR-vector, 8 lanes/row) ----------------
// h[v] = dis[v] * (sum_{e in in(v)} z[src_e] + z[v]);  y = (0.7h + 0.3 x0)*w
// act: 0=none 1=relu 2=leaky(0.01) 3=sigmoid 4=final(n*sigmoid -> int)

__global__ __launch_bounds__(256) void layer_kernel(
        const int* __restrict__ rp, const int* __restrict__ csr,
        const float* __restrict__ zin, const float* __restrict__ dis,
        const float* __restrict__ x0, const float* __restrict__ w,
        int li, int act, float* __restrict__ zout, int* __restrict__ out) {
    int tid = blockIdx.x * 256 + threadIdx.x;
    int v = tid >> 3;                                   // 8 lanes per row; grid sized exactly
    int lane = threadIdx.x & 7;
    int beg = rp[v];
    int end = rp[v + 1];
    float s = 0.f;
    for (int j = beg + lane; j < end; j += 8) s += zin[csr[j]];
    s += __shfl_xor(s, 1);
    s += __shfl_xor(s, 2);
    s += __shfl_xor(s, 4);
    if (lane != 0) return;
    s += zin[v];                                        // self loop
    float h = dis[v] * s;
    float comb = 0.7f * h + 0.3f * x0[v];
    float y = comb * w[li];
    if (act == 4) {
        float sg = 1.f / (1.f + expf(-y));
        out[v] = (int)(500000.f * sg);
        return;
    }
    float r;
    if (act == 0)      r = y;
    else if (act == 1) r = fmaxf(y, 0.f);
    else if (act == 2) r = (y > 0.f) ? y : 0.01f * y;
    else               r = 1.f / (1.f + expf(-y));      // sigmoid
    zout[v] = dis[v] * r;
}

// ---------------- launch ----------------

extern "C" void kernel_launch(void* const* d_in, const int* in_sizes, int n_in,
                              void* d_out, int out_size, void* d_ws, size_t ws_size,
                              hipStream_t stream) {
    const float* x0  = (const float*)d_in[0];
    const float* w   = (const float*)d_in[1];
    const int*   adj = (const int*)d_in[2];             // int32 (jax demotes int64)
    const int*   src = adj;
    const int*   dst = adj + NE;
    int* out = (int*)d_out;

    uintptr_t p = (uintptr_t)d_ws;
    auto alloc = [&](size_t bytes) -> void* {
        p = (p + 255) & ~(uintptr_t)255;
        void* r = (void*)p;
        p += bytes;
        return r;
    };
    float* dis    = (float*)alloc((size_t)NN * 4);
    int*   cnt    = (int*)alloc((size_t)NN * 4);
    int*   rp     = (int*)alloc((size_t)(NN + 1) * 4);
    int*   cursor = (int*)alloc((size_t)NN * 4);
    int*   bsum   = (int*)alloc((size_t)NB_SCAN * 4);
    float* z0     = (float*)alloc((size_t)NN * 4);
    float* z1     = (float*)alloc((size_t)NN * 4);
    int*   csr    = (int*)alloc((size_t)NE * 4);
    (void)ws_size;

    hipMemsetAsync(cnt, 0, (size_t)NN * 4, stream);

    const int EB = (NE / 4) / 256;                      // 15625, exact
    count_deg<<<EB, 256, 0, stream>>>((const int4*)dst, cnt);
    scan1<<<NB_SCAN, 256, 0, stream>>>(cnt, rp, bsum);
    scan2<<<1, 256, 0, stream>>>(bsum);
    finalize_scan<<<NB_SCAN, 256, 0, stream>>>(cnt, rp, bsum, cursor, dis);
    scatter_edges<<<EB, 256, 0, stream>>>((const int4*)src, (const int4*)dst, cursor, csr);
    init_z<<<NB_SCAN, 256, 0, stream>>>(x0, dis, z0);

    float* zbuf[2] = {z0, z1};
    const int LB = (NN * 8) / 256;                      // 15625, exact
    for (int i = 0; i < 49; i++) {
        int act;
        if (i == 0)            act = 0;
        else if (i == 48)      act = 4;
        else if (i % 10 == 1)  act = 2;                 // leaky {1,11,21,31,41}
        else if (i % 10 == 4)  act = 3;                 // sigmoid {4,14,24,34,44}
        else                   act = 1;                 // relu
        layer_kernel<<<LB, 256, 0, stream>>>(rp, csr, zbuf[i & 1], dis, x0, w,
                                             i, act, zbuf[(i + 1) & 1], out);
    }
}

// Round 2
// 4487.004 us; speedup vs baseline: 1.2719x; 1.2719x over previous
//
#include <hip/hip_runtime.h>
#include <math.h>

#define NN 500000
#define NE 16000000
#define NBKT 1954                 // ceil(NN/256): bucket = dst >> 8
#define PB 16384                  // edges per partition block
#define NPB_BLOCKS ((NE + PB - 1) / PB)   // 977
#define BKT_CAP 9216              // lambda=8192, +11 sigma

// ---------------- phase 1: bucket histogram ----------------
__global__ __launch_bounds__(256) void hist_kernel(const int4* __restrict__ dst4,
                                                   int* __restrict__ bcnt) {
    __shared__ int lh[NBKT];
    for (int i = threadIdx.x; i < NBKT; i += 256) lh[i] = 0;
    __syncthreads();
    long base4 = (long)blockIdx.x * (PB / 4);
    for (int k = 0; k < PB / 4; k += 256) {
        long i4 = base4 + k + threadIdx.x;
        if (i4 < NE / 4) {
            int4 d = dst4[i4];
            atomicAdd(&lh[d.x >> 8], 1);
            atomicAdd(&lh[d.y >> 8], 1);
            atomicAdd(&lh[d.z >> 8], 1);
            atomicAdd(&lh[d.w >> 8], 1);
        }
    }
    __syncthreads();
    for (int i = threadIdx.x; i < NBKT; i += 256) {
        int c = lh[i];
        if (c) atomicAdd(&bcnt[i], c);
    }
}

// ---------------- phase 2: exclusive scan of bucket counts ----------------
// in: bcnt = counts; out: bbase[i] = exclusive prefix, bbase[NBKT] = NE,
//     bcnt rewritten to the same base (partition cursor).
__global__ __launch_bounds__(256) void scan_buckets(int* __restrict__ bcnt,
                                                    int* __restrict__ bbase) {
    __shared__ int sh[256];
    __shared__ int carry_sh;
    if (threadIdx.x == 0) carry_sh = 0;
    __syncthreads();
    for (int base = 0; base < NBKT; base += 256) {
        int i = base + threadIdx.x;
        int v = (i < NBKT) ? bcnt[i] : 0;
        sh[threadIdx.x] = v;
        __syncthreads();
        for (int off = 1; off < 256; off <<= 1) {
            int t = (threadIdx.x >= off) ? sh[threadIdx.x - off] : 0;
            __syncthreads();
            sh[threadIdx.x] += t;
            __syncthreads();
        }
        int incl = sh[threadIdx.x];
        int c = carry_sh;
        __syncthreads();
        if (i < NBKT) {
            int ex = c + incl - v;
            bbase[i] = ex;
            bcnt[i] = ex;
        }
        if (threadIdx.x == 255) carry_sh = c + incl;
        __syncthreads();
    }
    if (threadIdx.x == 0) bbase[NBKT] = NE;
}

// ---------------- phase 3: partition edges into buckets ----------------
// ebuf[pos] = (dst&255)<<19 | src   (src < 2^19, dlo < 2^8)
__global__ __launch_bounds__(256) void partition_kernel(const int* __restrict__ src,
                                                        const int* __restrict__ dst,
                                                        int* __restrict__ bcur,
                                                        int* __restrict__ ebuf) {
    __shared__ int lh[NBKT];
    for (int i = threadIdx.x; i < NBKT; i += 256) lh[i] = 0;
    __syncthreads();
    long base = (long)blockIdx.x * PB;
    for (int k = 0; k < PB; k += 256) {
        long e = base + k + threadIdx.x;
        if (e < NE) atomicAdd(&lh[dst[e] >> 8], 1);
    }
    __syncthreads();
    for (int i = threadIdx.x; i < NBKT; i += 256) {
        int c = lh[i];
        if (c) lh[i] = atomicAdd(&bcur[i], c);   // reserve run; lh becomes cursor
    }
    __syncthreads();
    for (int k = 0; k < PB; k += 256) {
        long e = base + k + threadIdx.x;
        if (e < NE) {
            int d = dst[e];
            int pos = atomicAdd(&lh[d >> 8], 1);
            ebuf[pos] = ((d & 255) << 19) | src[e];
        }
    }
}

// ---------------- phase 4: per-bucket CSR build (in place) ----------------
__global__ __launch_bounds__(256) void bucket_csr(const int* __restrict__ bbase,
                                                  int* __restrict__ ebuf,   // == csr, in place
                                                  int* __restrict__ rp,
                                                  float* __restrict__ dis) {
    __shared__ int eds[BKT_CAP];
    __shared__ int cnt[256];
    __shared__ int scn[256];
    int b = blockIdx.x;
    int ebase = bbase[b];
    int nb = bbase[b + 1] - ebase;
    if (nb > BKT_CAP) nb = BKT_CAP;   // statistically impossible; guards LDS
    for (int i = threadIdx.x; i < nb; i += 256) eds[i] = ebuf[ebase + i];
    cnt[threadIdx.x] = 0;
    __syncthreads();
    for (int i = threadIdx.x; i < nb; i += 256) atomicAdd(&cnt[eds[i] >> 19], 1);
    __syncthreads();
    int my = cnt[threadIdx.x];
    scn[threadIdx.x] = my;
    __syncthreads();
    for (int off = 1; off < 256; off <<= 1) {
        int t = (threadIdx.x >= off) ? scn[threadIdx.x - off] : 0;
        __syncthreads();
        scn[threadIdx.x] += t;
        __syncthreads();
    }
    int excl = scn[threadIdx.x] - my;
    int v = b * 256 + threadIdx.x;
    if (v < NN) {
        rp[v] = ebase + excl;
        dis[v] = rsqrtf((float)(my + 1));       // +1 self loop
    }
    __syncthreads();
    cnt[threadIdx.x] = excl;                    // reuse as running cursor
    __syncthreads();
    for (int i = threadIdx.x; i < nb; i += 256) {
        int p = eds[i];
        int pos = atomicAdd(&cnt[p >> 19], 1);
        ebuf[ebase + pos] = p & 0x7FFFF;
    }
    if (b == 0 && threadIdx.x == 0) rp[NN] = NE;
}

__global__ void init_z(const float* __restrict__ x0, const float* __restrict__ dis,
                       float* __restrict__ z) {
    int i = blockIdx.x * 256 + threadIdx.x;
    if (i < NN) z[i] = x0[i] * dis[i];
}

// ---------------- per-layer SpMV (CSR-vector, 8 lanes/row) ----------------
// h[v] = dis[v] * (sum_{e in in(v)} z[src_e] + z[v]);  y = (0.7h + 0.3 x0)*w
// act: 0=none 1=relu 2=leaky(0.01) 3=sigmoid 4=final(n*sigmoid -> int)
__global__ __launch_bounds__(256) void layer_kernel(
        const int* __restrict__ rp, const int* __restrict__ csr,
        const float* __restrict__ zin, const float* __restrict__ dis,
        const float* __restrict__ x0, const float* __restrict__ w,
        int li, int act, float* __restrict__ zout, int* __restrict__ out) {
    int tid = blockIdx.x * 256 + threadIdx.x;
    int v = tid >> 3;                                   // 8 lanes per row; grid exact
    int lane = threadIdx.x & 7;
    int beg = rp[v];
    int end = rp[v + 1];
    float s = 0.f;
    for (int j = beg + lane; j < end; j += 8) s += zin[csr[j]];
    s += __shfl_xor(s, 1);
    s += __shfl_xor(s, 2);
    s += __shfl_xor(s, 4);
    if (lane != 0) return;
    s += zin[v];                                        // self loop
    float h = dis[v] * s;
    float comb = 0.7f * h + 0.3f * x0[v];
    float y = comb * w[li];
    if (act == 4) {
        float sg = 1.f / (1.f + expf(-y));
        out[v] = (int)(500000.f * sg);
        return;
    }
    float r;
    if (act == 0)      r = y;
    else if (act == 1) r = fmaxf(y, 0.f);
    else if (act == 2) r = (y > 0.f) ? y : 0.01f * y;
    else               r = 1.f / (1.f + expf(-y));      // sigmoid
    zout[v] = dis[v] * r;
}

// ---------------- launch ----------------
extern "C" void kernel_launch(void* const* d_in, const int* in_sizes, int n_in,
                              void* d_out, int out_size, void* d_ws, size_t ws_size,
                              hipStream_t stream) {
    const float* x0  = (const float*)d_in[0];
    const float* w   = (const float*)d_in[1];
    const int*   adj = (const int*)d_in[2];             // int32 (jax demotes int64)
    const int*   src = adj;
    const int*   dst = adj + NE;
    int* out = (int*)d_out;

    uintptr_t p = (uintptr_t)d_ws;
    auto alloc = [&](size_t bytes) -> void* {
        p = (p + 255) & ~(uintptr_t)255;
        void* r = (void*)p;
        p += bytes;
        return r;
    };
    float* dis   = (float*)alloc((size_t)NN * 4);
    int*   rp    = (int*)alloc((size_t)(NN + 1) * 4);
    float* z0    = (float*)alloc((size_t)NN * 4);
    float* z1    = (float*)alloc((size_t)NN * 4);
    int*   bcnt  = (int*)alloc((size_t)NBKT * 4);       // counts -> partition cursor
    int*   bbase = (int*)alloc((size_t)(NBKT + 1) * 4);
    int*   csr   = (int*)alloc((size_t)NE * 4);         // ebuf, rebuilt in place
    (void)ws_size;

    hipMemsetAsync(bcnt, 0, (size_t)NBKT * 4, stream);

    hist_kernel<<<NPB_BLOCKS, 256, 0, stream>>>((const int4*)dst, bcnt);
    scan_buckets<<<1, 256, 0, stream>>>(bcnt, bbase);
    partition_kernel<<<NPB_BLOCKS, 256, 0, stream>>>(src, dst, bcnt, csr);
    bucket_csr<<<NBKT, 256, 0, stream>>>(bbase, csr, rp, dis);
    init_z<<<(NN + 255) / 256, 256, 0, stream>>>(x0, dis, z0);

    float* zbuf[2] = {z0, z1};
    const int LB = (NN * 8) / 256;                      // 15625, exact
    for (int i = 0; i < 49; i++) {
        int act;
        if (i == 0)            act = 0;
        else if (i == 48)      act = 4;
        else if (i % 10 == 1)  act = 2;                 // leaky {1,11,21,31,41}
        else if (i % 10 == 4)  act = 3;                 // sigmoid {4,14,24,34,44}
        else                   act = 1;                 // relu
        layer_kernel<<<LB, 256, 0, stream>>>(rp, csr, zbuf[i & 1], dis, x0, w,
                                             i, act, zbuf[(i + 1) & 1], out);
    }
}